// Round 3
// baseline (238.023 us; speedup 1.0000x reference)
//
#include <hip/hip_runtime.h>

#define BATCH 16384
#define FEAT 2048
#define ROWS_PER_BLOCK 4                 // 4 waves (64 lanes) per 256-thread block
#define NBLK (BATCH / ROWS_PER_BLOCK)    // 4096 blocks

typedef float floatx4 __attribute__((ext_vector_type(4)));

// Fused kernel: one wave per row computes dist = ||x_b - c_{l_b}||^2 (clipped),
// block partial -> ws; the last block (atomic counter) tree-reduces all 4096
// partials deterministically and writes the mean. No second launch.
__global__ __launch_bounds__(256) void center_loss_fused(
    const float* __restrict__ x, const int* __restrict__ labels,
    const float* __restrict__ centers, float* __restrict__ out,
    float* __restrict__ ws)
{
    float* partials = ws;
    unsigned* counter = reinterpret_cast<unsigned*>(ws + NBLK);

    const int wave = threadIdx.x >> 6;
    const int lane = threadIdx.x & 63;
    const int row  = blockIdx.x * ROWS_PER_BLOCK + wave;   // grid covers BATCH exactly

    const floatx4* __restrict__ xr =
        reinterpret_cast<const floatx4*>(x + (size_t)row * FEAT);
    const int lbl = labels[row];
    const floatx4* __restrict__ cr =
        reinterpret_cast<const floatx4*>(centers + (size_t)lbl * FEAT);

    // Issue all 16 loads before any use: max memory-level parallelism.
    // x is streamed once -> non-temporal, keeps centers resident in L2/L3.
    floatx4 xv[8], cv[8];
#pragma unroll
    for (int j = 0; j < 8; ++j) xv[j] = __builtin_nontemporal_load(xr + lane + 64 * j);
#pragma unroll
    for (int j = 0; j < 8; ++j) cv[j] = cr[lane + 64 * j];

    float d = 0.f;
#pragma unroll
    for (int j = 0; j < 8; ++j) {
        const float a0 = xv[j].x - cv[j].x, a1 = xv[j].y - cv[j].y;
        const float a2 = xv[j].z - cv[j].z, a3 = xv[j].w - cv[j].w;
        d += a0 * a0 + a1 * a1 + a2 * a2 + a3 * a3;
    }

    // 64-lane butterfly reduce
#pragma unroll
    for (int off = 32; off; off >>= 1) d += __shfl_xor(d, off, 64);

    __shared__ float sdist[ROWS_PER_BLOCK];
    __shared__ bool  is_last;
    if (lane == 0) sdist[wave] = fminf(fmaxf(d, 1e-12f), 1e12f);  // per-row clip
    __syncthreads();

    if (threadIdx.x == 0) {
        partials[blockIdx.x] = sdist[0] + sdist[1] + sdist[2] + sdist[3];
        __threadfence();                       // partial visible device-wide
        unsigned t = atomicAdd(counter, 1u);   // device-scope
        is_last = (t == NBLK - 1);
    }
    __syncthreads();

    if (is_last) {
        __threadfence();
        const volatile float* vp = partials;   // cross-CU produced values
        float s = 0.f;
        for (int i = threadIdx.x; i < NBLK; i += 256) s += vp[i];
        __shared__ float sm[256];
        sm[threadIdx.x] = s;
        __syncthreads();
#pragma unroll
        for (int off = 128; off; off >>= 1) {
            if (threadIdx.x < off) sm[threadIdx.x] += sm[threadIdx.x + off];
            __syncthreads();
        }
        if (threadIdx.x == 0) out[0] = sm[0] / (float)BATCH;
    }
}

extern "C" void kernel_launch(void* const* d_in, const int* in_sizes, int n_in,
                              void* d_out, int out_size, void* d_ws, size_t ws_size,
                              hipStream_t stream) {
    const float* x       = (const float*)d_in[0];   // [BATCH, FEAT] f32
    const int*   labels  = (const int*)d_in[1];     // [BATCH] int
    const float* centers = (const float*)d_in[2];   // [NUM_CLASSES, FEAT] f32
    float* out      = (float*)d_out;
    float* ws       = (float*)d_ws;                 // NBLK partials + 1 counter

    // zero the arrival counter each call (deterministic across graph replays)
    (void)hipMemsetAsync((char*)d_ws + NBLK * sizeof(float), 0, sizeof(unsigned), stream);
    center_loss_fused<<<NBLK, 256, 0, stream>>>(x, labels, centers, out, ws);
}

// Round 4
// 42.358 us; speedup vs baseline: 5.6193x; 5.6193x over previous
//
#include <hip/hip_runtime.h>

#define BATCH 16384
#define FEAT 2048
#define ROWS_PER_BLOCK 4                 // 4 waves (64 lanes) per 256-thread block
#define NBLK (BATCH / ROWS_PER_BLOCK)    // 4096 blocks

typedef float floatx4 __attribute__((ext_vector_type(4)));

// Kernel 1: one wave per row. dist = ||x_b - c_{l_b}||^2, clipped.
// One partial (sum of 4 rows) per block -> ws. No fences, no atomics.
__global__ __launch_bounds__(256) void center_loss_rows(
    const float* __restrict__ x, const int* __restrict__ labels,
    const float* __restrict__ centers, float* __restrict__ partials)
{
    const int wave = threadIdx.x >> 6;
    const int lane = threadIdx.x & 63;
    const int row  = blockIdx.x * ROWS_PER_BLOCK + wave;   // grid covers BATCH exactly

    const floatx4* __restrict__ xr =
        reinterpret_cast<const floatx4*>(x + (size_t)row * FEAT);
    const int lbl = labels[row];
    const floatx4* __restrict__ cr =
        reinterpret_cast<const floatx4*>(centers + (size_t)lbl * FEAT);

    // Issue all 16 loads before any use: max memory-level parallelism.
    floatx4 xv[8], cv[8];
#pragma unroll
    for (int j = 0; j < 8; ++j) xv[j] = xr[lane + 64 * j];
#pragma unroll
    for (int j = 0; j < 8; ++j) cv[j] = cr[lane + 64 * j];

    float d = 0.f;
#pragma unroll
    for (int j = 0; j < 8; ++j) {
        const float a0 = xv[j].x - cv[j].x, a1 = xv[j].y - cv[j].y;
        const float a2 = xv[j].z - cv[j].z, a3 = xv[j].w - cv[j].w;
        d += a0 * a0 + a1 * a1 + a2 * a2 + a3 * a3;
    }

    // 64-lane butterfly reduce (single accumulator -> 6 shuffles)
#pragma unroll
    for (int off = 32; off; off >>= 1) d += __shfl_xor(d, off, 64);

    __shared__ float sdist[ROWS_PER_BLOCK];
    if (lane == 0) sdist[wave] = fminf(fmaxf(d, 1e-12f), 1e12f);  // per-row clip
    __syncthreads();
    if (threadIdx.x == 0)
        partials[blockIdx.x] = sdist[0] + sdist[1] + sdist[2] + sdist[3];
}

// Kernel 2: deterministic tree reduction of the 4096 block partials -> mean.
__global__ __launch_bounds__(256) void reduce_partials(
    const float* __restrict__ partials, float* __restrict__ out, int n)
{
    float s = 0.f;
    for (int i = threadIdx.x; i < n; i += 256) s += partials[i];
    __shared__ float sm[256];
    sm[threadIdx.x] = s;
    __syncthreads();
#pragma unroll
    for (int off = 128; off; off >>= 1) {
        if (threadIdx.x < off) sm[threadIdx.x] += sm[threadIdx.x + off];
        __syncthreads();
    }
    if (threadIdx.x == 0) out[0] = sm[0] / (float)BATCH;
}

extern "C" void kernel_launch(void* const* d_in, const int* in_sizes, int n_in,
                              void* d_out, int out_size, void* d_ws, size_t ws_size,
                              hipStream_t stream) {
    const float* x       = (const float*)d_in[0];   // [BATCH, FEAT] f32
    const int*   labels  = (const int*)d_in[1];     // [BATCH] int
    const float* centers = (const float*)d_in[2];   // [NUM_CLASSES, FEAT] f32
    float* out      = (float*)d_out;
    float* partials = (float*)d_ws;                 // 4096 floats

    center_loss_rows<<<NBLK, 256, 0, stream>>>(x, labels, centers, partials);
    reduce_partials<<<1, 256, 0, stream>>>(partials, out, NBLK);
}